// Round 2
// baseline (564.199 us; speedup 1.0000x reference)
//
#include <hip/hip_runtime.h>

#define K_TAGS 50
#define T_MAX 256
#define START_TAG 48
#define END_TAG 49
#define LOG2E 1.4426950408889634f
#define LN2 0.6931471805599453f

// hardware transcendentals: v_exp_f32 is 2^x, v_log_f32 is log2(x)
#define EXP2F(x) __builtin_amdgcn_exp2f(x)
#define LOG2F(x) __builtin_amdgcn_logf(x)

// One block per batch element. 512 threads = 8 waves.
// Lane j (j<50) owns output column j; wave w owns rows i == w (mod 8).
// Forward recursion kept in log2 domain; block-uniform max subtraction (M = beta[0]).
// LDS: 3 rotating column-sum buffers -> exactly ONE __syncthreads per timestep.
// Scores prefetched 3 steps ahead into registers (plain global->VGPR loads, so the
// barrier should not drain vmcnt).
__global__ __launch_bounds__(512, 1) void crf_fwd_kernel(
    const float* __restrict__ scores, const int* __restrict__ targets,
    const int* __restrict__ lengths, float* __restrict__ accum)
{
    const int b    = blockIdx.x;
    const int tid  = threadIdx.x;
    const int wave = tid >> 6;
    const int lane = tid & 63;
    const int len  = lengths[b];
    const float* __restrict__ sp = scores + (size_t)b * T_MAX * K_TAGS * K_TAGS;

    // ---------------- gold score (threads 0..255 handle t = tid) ----------------
    if (tid < T_MAX) {
        float g = 0.f;
        if (tid < len) {
            int tg = targets[b * T_MAX + tid];
            g = sp[(size_t)tid * (K_TAGS * K_TAGS) + tg];
        }
        #pragma unroll
        for (int off = 32; off > 0; off >>= 1) g += __shfl_down(g, off, 64);
        if (lane == 0) atomicAdd(&accum[1], g);
    }

    // ---------------- forward recursion ----------------
    __shared__ float csum[3][64];
    if (tid < 192) csum[tid >> 6][tid & 63] = 0.f;

    int rows[7];
    #pragma unroll
    for (int k = 0; k < 7; ++k) rows[k] = wave + 8 * k;   // rows[6] may be >= 50 (masked via bu)

    const int lanec = (lane < K_TAGS) ? lane : (K_TAGS - 1);  // clamp keeps loads in-bounds

    // Issue this wave's row elements for timestep t (clamped) into dst registers.
    auto issue = [&](float (&dst)[7], int t) {
        int tc = (t < len) ? t : (len - 1);
        const float* s = sp + (size_t)tc * (K_TAGS * K_TAGS);
        #pragma unroll
        for (int k = 0; k < 7; ++k) {
            int i = rows[k];
            dst[k] = s[(i < K_TAGS ? i : 0) * K_TAGS + lanec];  // unconditional, clamped
        }
    };

    // beta0 (log2 domain): lane j holds beta[j] = scores[b,0,START,j] * log2(e)
    float bcur = sp[START_TAG * K_TAGS + lanec] * LOG2E;
    float M = __shfl(bcur, 0, 64);
    float bu[7];
    #pragma unroll
    for (int k = 0; k < 7; ++k) {
        int i = rows[k];
        float v = __shfl(bcur, (i < K_TAGS) ? i : 0, 64);
        bu[k] = (i < K_TAGS) ? (v - M) : -1e30f;   // -inf rows contribute exp2 -> 0
    }

    float sA[7], sB[7], sC[7];
    issue(sA, 1); issue(sB, 2); issue(sC, 3);

    __syncthreads();  // B(0): csum zeroed before epoch-1 adds

    // One epoch = one timestep e. ADD/RD/ZR are the compile-time csum phase indices.
    auto epoch = [&](float (&sc)[7], int e, int ADD, int RD, int ZR) {
        if (e >= 2) {
            // merge beta_{e-1} from the column sums accumulated last epoch
            float cs = csum[RD][lane];
            float na = M + LOG2F(cs);              // lane j: beta_{e-1}[j]
            float Mn = __shfl(na, 0, 64);
            #pragma unroll
            for (int k = 0; k < 7; ++k) {
                int i = rows[k];
                float v = __shfl(na, (i < K_TAGS) ? i : 0, 64);
                bu[k] = (i < K_TAGS) ? (v - Mn) : -1e30f;
            }
            M = Mn;
        }
        csum[ZR][lane] = 0.f;                      // buffer for epoch e+1 (race-free: R/W epochs differ)
        float a = 0.f;
        #pragma unroll
        for (int k = 0; k < 7; ++k)
            a += EXP2F(__builtin_fmaf(sc[k], LOG2E, bu[k]));
        atomicAdd(&csum[ADD][lane], a);            // partial merge across the 8 waves
        issue(sc, e + 3);                          // refill this register set, 3 steps ahead
        __syncthreads();
    };

    int t = 1;
    while (t < len) {
        epoch(sA, t, 1, 0, 2); if (++t >= len) break;   // e%3==1
        epoch(sB, t, 2, 1, 0); if (++t >= len) break;   // e%3==2
        epoch(sC, t, 0, 2, 1); ++t;                     // e%3==0
    }

    float beta_end;
    if (len >= 2) {
        int idx = (len - 1) % 3;
        beta_end = M + LOG2F(csum[idx][lane]);
    } else {
        beta_end = bcur;
    }
    if (tid == END_TAG)                       // wave 0, lane 49 holds beta_final[END_TAG]
        atomicAdd(&accum[0], beta_end * LN2); // back to natural log

}

__global__ void finalize_kernel(const float* __restrict__ accum,
                                float* __restrict__ out, float invB)
{
    out[0] = (accum[0] - accum[1]) * invB;
}

extern "C" void kernel_launch(void* const* d_in, const int* in_sizes, int n_in,
                              void* d_out, int out_size, void* d_ws, size_t ws_size,
                              hipStream_t stream)
{
    const float* scores  = (const float*)d_in[0];
    const int*   targets = (const int*)d_in[1];
    const int*   lengths = (const int*)d_in[2];
    const int B = in_sizes[2];

    float* accum = (float*)d_ws;
    hipMemsetAsync(accum, 0, 2 * sizeof(float), stream);
    crf_fwd_kernel<<<B, 512, 0, stream>>>(scores, targets, lengths, accum);
    finalize_kernel<<<1, 1, 0, stream>>>(accum, (float*)d_out, 1.0f / (float)B);
}